// Round 8
// baseline (114.870 us; speedup 1.0000x reference)
//
#include <hip/hip_runtime.h>

// RoI crop_and_resize (tf.image.crop_and_resize, bilinear), single image.
// feature: [1,50,50,1024] f32; rois: [512,4] f32; img_size: [2] i32.
// Output: [512,14,14,1024] f32.
//
// R7: exactly R5 (best: 80.7us) but with PLAIN stores instead of
// __builtin_nontemporal_store — A/B of the NT write path. NT bypasses L2;
// rocclr memset (plain stores, L2 writeback) sustains 6.8 TB/s while our NT
// stream ran at 5.1 TB/s. Feature slice (2.56MB/XCD) has high temporal
// locality vs touch-once write lines, so L2 LRU should keep it resident.
//
// Structure: block = (RoI n, 64-channel slice s), bid = 16n + s -> slice s
// runs on XCD s&7, each XCD reads only 2/16 channel slices = 1.28 MB,
// L2-resident. No LDS: 64-ch row-pair window ~25KB -> L1-resident.

#define FH 50
#define FW 50
#define FC 1024
#define PH 14
#define PW 14
#define CS 64                 // channels per slice
#define NSL (FC / CS)         // 16 slices
#define QS (CS / 4)           // 16 f32x4 quads per slice

typedef float f32x4 __attribute__((ext_vector_type(4)));

__global__ __launch_bounds__(256) void roi_crop_resize_kernel(
    const float* __restrict__ feat,
    const float* __restrict__ rois,
    const int* __restrict__ img_size,
    float* __restrict__ out)
{
    int bid = blockIdx.x;
    int n = bid >> 4;          // RoI index
    int s = bid & (NSL - 1);   // channel slice -> XCD s&7
    int t = threadIdx.x;
    int q = t & 15;            // quad within slice (16 x f32x4 = 64 ch)
    int j = t >> 4;            // 0..15; j<14 active for compute

    float hs = (float)img_size[0];
    float ws = (float)img_size[1];
    float by1 = rois[n * 4 + 0] / hs;
    float bx1 = rois[n * 4 + 1] / ws;
    float by2 = rois[n * 4 + 2] / hs;
    float bx2 = rois[n * 4 + 3] / ws;

    float ybase = by1 * (float)(FH - 1);
    float dy    = (by2 - by1) * (float)(FH - 1) * (1.0f / (float)(PH - 1));
    float xbase = bx1 * (float)(FW - 1);
    float dxs   = (bx2 - bx1) * (float)(FW - 1) * (1.0f / (float)(PW - 1));

    // per-lane x interpolation (clamped so inactive lanes form valid addrs)
    float xs  = xbase + (float)j * dxs;
    float x0f = floorf(xs);
    float wx  = xs - x0f;
    int x0 = (int)fminf(fmaxf(x0f,        0.0f), (float)(FW - 1));
    int x1 = (int)fminf(fmaxf(x0f + 1.0f, 0.0f), (float)(FW - 1));
    float omwx = 1.0f - wx;

    const f32x4* fq = (const f32x4*)feat;
    int sq = s * QS + q;                       // quad index within a pixel
    f32x4* ob = (f32x4*)out + ((size_t)n * (PH * PW)) * (FC / 4) + sq;

    bool active = (j < PW);

    #pragma unroll
    for (int i = 0; i < PH; ++i) {
        float ysf = ybase + (float)i * dy;
        float y0f = floorf(ysf);
        float wy  = ysf - y0f;
        int r0 = (int)fminf(fmaxf(y0f,        0.0f), (float)(FH - 1));
        int r1 = (int)fminf(fmaxf(y0f + 1.0f, 0.0f), (float)(FH - 1));
        float omwy = 1.0f - wy;

        if (active) {
            int bT = (r0 * FW) * (FC / 4) + sq;
            int bB = (r1 * FW) * (FC / 4) + sq;
            f32x4 a = fq[bT + x0 * (FC / 4)];
            f32x4 b = fq[bT + x1 * (FC / 4)];
            f32x4 c = fq[bB + x0 * (FC / 4)];
            f32x4 d = fq[bB + x1 * (FC / 4)];

            // reference ordering: top = a*(1-wx)+b*wx; bot = c*(1-wx)+d*wx;
            // out = top*(1-wy) + bot*wy
            f32x4 res = (a * omwx + b * wx) * omwy + (c * omwx + d * wx) * wy;

            ob[(i * PW + j) * (FC / 4)] = res;
        }
    }
}

extern "C" void kernel_launch(void* const* d_in, const int* in_sizes, int n_in,
                              void* d_out, int out_size, void* d_ws, size_t ws_size,
                              hipStream_t stream) {
    const float* feat     = (const float*)d_in[0];
    const float* rois     = (const float*)d_in[1];
    const int*   img_size = (const int*)d_in[2];
    float* out = (float*)d_out;

    int n_rois = in_sizes[1] / 4;            // 512
    int grid   = n_rois * NSL;               // 8192 blocks

    roi_crop_resize_kernel<<<grid, 256, 0, stream>>>(feat, rois, img_size, out);
}